// Round 1
// baseline (19292.319 us; speedup 1.0000x reference)
//
#include <hip/hip_runtime.h>
#include <math.h>

// Problem constants (match reference)
constexpr int NB = 32;      // batch
constexpr int NC = 64;      // channels (CIN == CH)
constexpr int IH = 128;
constexpr int IW = 128;
constexpr int PLANE = IH * IW;          // 16384
constexpr int CHW = NC * PLANE;         // 1048576 = 1<<20
constexpr long long HALF = (long long)NB * CHW;  // 33554432
constexpr float EPS = 1e-5f;

// Tiling for kernel A
constexpr int TH = 8;
constexpr int TW = 8;
constexpr int NPIX = TH * TW;           // 64 pixels = one wave
constexpr int HH = TH + 4;              // halo rows (12)
constexpr int HW = TW + 4;              // halo cols (12)

__device__ __forceinline__ float sigmoidf_(float z) {
    return 1.0f / (1.0f + __expf(-z));
}

// Kernel A: fused gates + 5x5 exc/inh convs + c_next, plus per-batch sum/sumsq
// of c_next for the LayerNorm. Writes o-gate into out[0:HALF] (overwritten by
// kernel B with h_next) and c_next into out[HALF:2*HALF].
__global__ __launch_bounds__(256, 2)
void fused_cell_a(const float* __restrict__ x, const float* __restrict__ h,
                  const float* __restrict__ c,
                  const float* __restrict__ w_xg, const float* __restrict__ b_xg,
                  const float* __restrict__ w_hg, const float* __restrict__ b_hg,
                  const float* __restrict__ w_exc, const float* __restrict__ b_exc,
                  const float* __restrict__ w_inh, const float* __restrict__ b_inh,
                  float* __restrict__ out, float* __restrict__ ws)
{
    __shared__ float sh_h[NC][HH][HW];   // 64*12*12 = 9216 floats (36.9 KB)
    __shared__ float sh_x[NC][NPIX];     // 4096 floats (16 KB)
    __shared__ float red_s[4], red_q[4];

    const int tid = threadIdx.x;
    const int blk = blockIdx.x;                 // 0..8191
    const int tiles_x = IW / TW;                // 16
    const int tiles_y = IH / TH;                // 16
    const int tile = blk % (tiles_x * tiles_y);
    const int b    = blk / (tiles_x * tiles_y);
    const int ty0  = (tile / tiles_x) * TH;
    const int tx0  = (tile % tiles_x) * TW;

    // ---- stage h halo tile ----
    const float* hb = h + (size_t)b * CHW;
    for (int e = tid; e < NC * HH * HW; e += 256) {
        int ci  = e / (HH * HW);
        int rem = e - ci * (HH * HW);
        int r   = rem / HW;
        int cc  = rem - r * HW;
        int gy = ty0 + r - 2, gx = tx0 + cc - 2;
        float v = 0.0f;
        if ((unsigned)gy < (unsigned)IH && (unsigned)gx < (unsigned)IW)
            v = hb[ci * PLANE + gy * IW + gx];
        sh_h[ci][r][cc] = v;
    }
    // ---- stage x tile ----
    const float* xb = x + (size_t)b * CHW;
    for (int e = tid; e < NC * NPIX; e += 256) {
        int ci = e >> 6;
        int p  = e & 63;
        int py = p >> 3, px = p & 7;
        sh_x[ci][p] = xb[ci * PLANE + (ty0 + py) * IW + (tx0 + px)];
    }
    __syncthreads();

    const int p  = tid & 63;        // pixel within tile == lane id
    const int py = p >> 3;
    const int px = p & 7;
    const int wv = tid >> 6;        // wave id == co-group
    const int co0 = __builtin_amdgcn_readfirstlane(wv * 16);  // wave-uniform

    float aexc[16], ainh[16], agi[16], agf[16], ago[16];
#pragma unroll
    for (int j = 0; j < 16; ++j) {
        aexc[j] = 0.f; ainh[j] = 0.f; agi[j] = 0.f; agf[j] = 0.f; ago[j] = 0.f;
    }

    for (int ci = 0; ci < NC; ++ci) {
        float hv[25];
#pragma unroll
        for (int dy = 0; dy < 5; ++dy)
#pragma unroll
            for (int dx = 0; dx < 5; ++dx)
                hv[dy * 5 + dx] = sh_h[ci][py + dy][px + dx];
        const float xv  = sh_x[ci][p];
        const float hcv = hv[12];   // center tap = h[ci] at this pixel

#pragma unroll
        for (int j = 0; j < 16; ++j) {
            const int co = co0 + j;
            const float* we = w_exc + ((size_t)co * NC + ci) * 25;
            const float* wi = w_inh + ((size_t)co * NC + ci) * 25;
            float se = 0.f, si = 0.f;
#pragma unroll
            for (int t = 0; t < 25; ++t) {
                se = fmaf(we[t], hv[t], se);
                si = fmaf(wi[t], hv[t], si);
            }
            aexc[j] += se;
            ainh[j] += si;
            agi[j] = fmaf(w_xg[(co      ) * NC + ci], xv,  agi[j]);
            agi[j] = fmaf(w_hg[(co      ) * NC + ci], hcv, agi[j]);
            agf[j] = fmaf(w_xg[(co +  64) * NC + ci], xv,  agf[j]);
            agf[j] = fmaf(w_hg[(co +  64) * NC + ci], hcv, agf[j]);
            ago[j] = fmaf(w_xg[(co + 128) * NC + ci], xv,  ago[j]);
            ago[j] = fmaf(w_hg[(co + 128) * NC + ci], hcv, ago[j]);
        }
    }

    // ---- epilogue: gating, c_next, stores, reduction ----
    const float* cb = c + (size_t)b * CHW;
    const int gy = ty0 + py, gx = tx0 + px;
    float lsum = 0.f, lsq = 0.f;
#pragma unroll
    for (int j = 0; j < 16; ++j) {
        const int co = co0 + j;
        float ig = sigmoidf_(agi[j] + b_xg[co]       + b_hg[co]);
        float fg = sigmoidf_(agf[j] + b_xg[co +  64] + b_hg[co +  64]);
        float og = sigmoidf_(ago[j] + b_xg[co + 128] + b_hg[co + 128]);
        float ev = aexc[j] + b_exc[co];
        float iv = ainh[j] + b_inh[co];
        float hcenter = sh_h[co][py + 2][px + 2];
        float hor = sigmoidf_(-iv) * (hcenter + ev);
        float cold = cb[(size_t)co * PLANE + gy * IW + gx];
        float cn = fg * cold + ig * hor;
        size_t oidx = (size_t)b * CHW + (size_t)co * PLANE + (size_t)gy * IW + gx;
        out[oidx]        = og;   // o-gate parked in h_next slot
        out[HALF + oidx] = cn;   // c_next (final)
        lsum += cn;
        lsq  += cn * cn;
    }

    // wave (64-lane) reduction then cross-wave via LDS
#pragma unroll
    for (int off = 32; off > 0; off >>= 1) {
        lsum += __shfl_down(lsum, off, 64);
        lsq  += __shfl_down(lsq,  off, 64);
    }
    if ((tid & 63) == 0) { red_s[wv] = lsum; red_q[wv] = lsq; }
    __syncthreads();
    if (tid == 0) {
        float s = red_s[0] + red_s[1] + red_s[2] + red_s[3];
        float q = red_q[0] + red_q[1] + red_q[2] + red_q[3];
        atomicAdd(&ws[2 * b],     s);
        atomicAdd(&ws[2 * b + 1], q);
    }
}

// Kernel B: per-batch LayerNorm of c_next + tanh, h_next = o * tanh(norm).
// In-place on out[0:HALF] (o-gate -> h_next), reads c_next from out[HALF:].
__global__ __launch_bounds__(256)
void fused_cell_b(float* __restrict__ out, const float* __restrict__ ws)
{
    const float invN = 1.0f / (float)CHW;
    size_t i4  = (size_t)blockIdx.x * 256 + threadIdx.x;
    size_t idx = i4 * 4;
    int b = (int)(idx >> 20);          // CHW == 1<<20
    float s = ws[2 * b], q = ws[2 * b + 1];
    float mean = s * invN;
    float var  = q * invN - mean * mean;
    float r    = rsqrtf(var + EPS);

    float4 o  = *(const float4*)(out + idx);
    float4 cn = *(const float4*)(out + HALF + idx);
    float4 hn;
    hn.x = o.x * tanhf((cn.x - mean) * r);
    hn.y = o.y * tanhf((cn.y - mean) * r);
    hn.z = o.z * tanhf((cn.z - mean) * r);
    hn.w = o.w * tanhf((cn.w - mean) * r);
    *(float4*)(out + idx) = hn;
}

extern "C" void kernel_launch(void* const* d_in, const int* in_sizes, int n_in,
                              void* d_out, int out_size, void* d_ws, size_t ws_size,
                              hipStream_t stream) {
    const float* x     = (const float*)d_in[0];
    const float* h     = (const float*)d_in[1];
    const float* c     = (const float*)d_in[2];
    const float* w_xg  = (const float*)d_in[3];
    const float* b_xg  = (const float*)d_in[4];
    const float* w_hg  = (const float*)d_in[5];
    const float* b_hg  = (const float*)d_in[6];
    const float* w_exc = (const float*)d_in[7];
    const float* b_exc = (const float*)d_in[8];
    const float* w_inh = (const float*)d_in[9];
    const float* b_inh = (const float*)d_in[10];
    float* out = (float*)d_out;
    float* ws  = (float*)d_ws;

    // zero the per-batch (sum, sumsq) accumulators
    hipMemsetAsync(ws, 0, 2 * NB * sizeof(float), stream);

    dim3 blkA(256), grdA(NB * (IH / TH) * (IW / TW));   // 32*16*16 = 8192
    fused_cell_a<<<grdA, blkA, 0, stream>>>(x, h, c, w_xg, b_xg, w_hg, b_hg,
                                            w_exc, b_exc, w_inh, b_inh, out, ws);

    dim3 blkB(256), grdB((unsigned)(HALF / 4 / 256));   // 32768
    fused_cell_b<<<grdB, blkB, 0, stream>>>(out, ws);
}

// Round 2
// 1180.359 us; speedup vs baseline: 16.3445x; 16.3445x over previous
//
#include <hip/hip_runtime.h>
#include <math.h>

typedef short s16x8 __attribute__((ext_vector_type(8)));
typedef float f32x4 __attribute__((ext_vector_type(4)));

constexpr int NB = 32, CI = 64, IH = 128, IW = 128;
constexpr int PLANE = IH * IW;                 // 16384
constexpr int CHW = CI * PLANE;                // 1<<20
constexpr long long HALF = (long long)NB * CHW;
constexpr float EPS = 1e-5f;

// ws byte offsets
constexpr size_t WS_WCONV = 256;               // ushort[2][25][64][64]   (409,600 B)
constexpr size_t WS_WGATE = 409856;            // ushort[192][128]        (49,152 B)
constexpr size_t WS_XN = (size_t)1 << 20;      // x NHWC bf16 (64 MB)
constexpr size_t WS_HN = ((size_t)1 << 20) + ((size_t)64 << 20); // h NHWC bf16

__device__ __forceinline__ ushort f2bf(float f) {
    unsigned u = __float_as_uint(f);
    return (ushort)((u + 0x7fffu + ((u >> 16) & 1u)) >> 16);
}
__device__ __forceinline__ float bf2f(ushort h) { return __uint_as_float(((unsigned)h) << 16); }
__device__ __forceinline__ float sigf(float z) { return 1.0f / (1.0f + __expf(-z)); }
__device__ __forceinline__ float tanhfast(float z) { return 1.0f - 2.0f / (__expf(2.0f * z) + 1.0f); }
#define MFMA(a, b, c) __builtin_amdgcn_mfma_f32_16x16x32_bf16(a, b, c, 0, 0, 0)

// ---- pre-pass: weights -> bf16, MFMA-friendly layouts ----
// wconv[cv][tap][co][ci], wgate[n][k] (k = 0..63 x-ci, 64..127 h-ci)
__global__ __launch_bounds__(256) void k_prep_w(
    const float* __restrict__ w_xg, const float* __restrict__ w_hg,
    const float* __restrict__ w_exc, const float* __restrict__ w_inh,
    ushort* __restrict__ wconv, ushort* __restrict__ wgate)
{
    int idx = blockIdx.x * 256 + threadIdx.x;
    if (idx < 204800) {
        int cv = idx / 102400;
        int rem = idx - cv * 102400;
        int t = rem >> 12;
        int rem2 = rem & 4095;
        int co = rem2 >> 6, ci = rem2 & 63;
        const float* src = cv ? w_inh : w_exc;
        wconv[idx] = f2bf(src[(co * 64 + ci) * 25 + t]);
    } else if (idx < 204800 + 24576) {
        int g = idx - 204800;
        int n = g >> 7, k = g & 127;
        float v = (k < 64) ? w_xg[n * 64 + k] : w_hg[n * 64 + (k - 64)];
        wgate[g] = f2bf(v);
    }
}

// ---- pre-pass: x,h NCHW fp32 -> NHWC bf16 ----
__global__ __launch_bounds__(256) void k_nhwc(const float* __restrict__ x,
    const float* __restrict__ h, ushort* __restrict__ xn, ushort* __restrict__ hn)
{
    __shared__ float t[64][129];
    int bid = blockIdx.x;
    const float* src; ushort* dst;
    if (bid < 4096) { src = x; dst = xn; } else { src = h; dst = hn; bid -= 4096; }
    int b = bid >> 7, y = bid & 127;
    const float* s0 = src + (size_t)b * CHW + y * IW;
    for (int e = threadIdx.x; e < 8192; e += 256) {
        int ci = e >> 7, xx = e & 127;
        t[ci][xx] = s0[(size_t)ci * PLANE + xx];
    }
    __syncthreads();
    ushort* d0 = dst + ((size_t)(b * IH + y)) * IW * 64;
    for (int e = threadIdx.x; e < 8192; e += 256) {
        int xx = e >> 6, ci = e & 63;
        d0[e] = f2bf(t[ci][xx]);
    }
}

// ---- main fused cell: gates GEMM + 5x5 exc/inh implicit GEMM + epilogue ----
__global__ __launch_bounds__(256, 2) void k_cell(
    const ushort* __restrict__ xn, const ushort* __restrict__ hn,
    const float* __restrict__ c,
    const ushort* __restrict__ wconv, const ushort* __restrict__ wgate,
    const float* __restrict__ b_xg, const float* __restrict__ b_hg,
    const float* __restrict__ b_exc, const float* __restrict__ b_inh,
    float* __restrict__ out, float* __restrict__ red)
{
    __shared__ ushort sm[32768];      // 64 KB, multi-purpose
    __shared__ float reds[4], redq[4];
    const int tid = threadIdx.x;
    const int w = tid >> 6, lane = tid & 63;
    const int n16 = lane & 15, quad = lane >> 4;
    const int b = blockIdx.x >> 7, y = blockIdx.x & 127;
    const ushort* xrow = xn + ((size_t)(b * IH + y)) * IW * 64;
    const ushort* hrow = hn + ((size_t)(b * IH + y)) * IW * 64;

    // ---- phase 1: stage x-row and h-center-row ----
    for (int e = tid; e < 2048; e += 256) {
        int which = e >> 10, i8 = (e & 1023) * 8;
        const ushort* s = which ? hrow : xrow;
        *(s16x8*)(sm + which * 8192 + i8) = *(const s16x8*)(s + i8);
    }
    __syncthreads();

    // gate GEMM: M=32 (this wave), N=192 (12 tiles), K=128
    const int pm0 = w * 32;
    f32x4 accG[2][12];
#pragma unroll
    for (int m = 0; m < 2; ++m)
#pragma unroll
        for (int g = 0; g < 12; ++g) accG[m][g] = (f32x4){0.f, 0.f, 0.f, 0.f};

#pragma unroll
    for (int kb = 0; kb < 4; ++kb) {
        const ushort* ab = sm + (kb >= 2 ? 8192 : 0);
        int ko = (kb & 1) * 32;
        s16x8 a0 = *(const s16x8*)(ab + (pm0 + n16) * 64 + ko + quad * 8);
        s16x8 a1 = *(const s16x8*)(ab + (pm0 + 16 + n16) * 64 + ko + quad * 8);
#pragma unroll
        for (int g = 0; g < 12; ++g) {
            s16x8 bb = *(const s16x8*)(wgate + (g * 16 + n16) * 128 + kb * 32 + quad * 8);
            accG[0][g] = MFMA(a0, bb, accG[0][g]);
            accG[1][g] = MFMA(a1, bb, accG[1][g]);
        }
    }

    // sigmoid; write o-gate now (final consumer is k_norm); pack i,f as bf16x2
    unsigned packIF[2][4][4];
#pragma unroll
    for (int mt = 0; mt < 2; ++mt)
#pragma unroll
        for (int ct = 0; ct < 4; ++ct) {
            int co = ct * 16 + n16;
            float bi = b_xg[co] + b_hg[co];
            float bff = b_xg[64 + co] + b_hg[64 + co];
            float bo = b_xg[128 + co] + b_hg[128 + co];
#pragma unroll
            for (int r = 0; r < 4; ++r) {
                int p = pm0 + mt * 16 + quad * 4 + r;
                float ig = sigf(accG[mt][ct][r] + bi);
                float fg = sigf(accG[mt][ct + 4][r] + bff);
                float og = sigf(accG[mt][ct + 8][r] + bo);
                out[(size_t)b * CHW + (size_t)co * PLANE + y * IW + p] = og;
                packIF[mt][ct][r] = (unsigned)f2bf(ig) | ((unsigned)f2bf(fg) << 16);
            }
        }

    // ---- phase 2: conv GEMM, square wave-split: mh = pixel half, cv = exc/inh ----
    const int mh = w & 1, cv = w >> 1;
    const int pmc = mh * 64;
    f32x4 accC[4][4];
#pragma unroll
    for (int m = 0; m < 4; ++m)
#pragma unroll
        for (int n = 0; n < 4; ++n) accC[m][n] = (f32x4){0.f, 0.f, 0.f, 0.f};

    for (int ch = 0; ch < 2; ++ch) {
        const int ci0 = ch * 32;
        __syncthreads();
        // stage 5 halo rows x 132 x 32ci as [dy][xi][ci] bf16
        for (int e = tid; e < 2640; e += 256) {
            int dy = e / 528;
            int rem = e - dy * 528;
            int xi = rem >> 2, cg = rem & 3;
            int yy = y + dy - 2, gx = xi - 2;
            s16x8 v = {0, 0, 0, 0, 0, 0, 0, 0};
            if ((unsigned)yy < 128u && (unsigned)gx < 128u)
                v = *(const s16x8*)(hn + (((size_t)(b * IH + yy)) * IW + gx) * 64 + ci0 + cg * 8);
            *(s16x8*)(sm + (dy * 132 + xi) * 32 + cg * 8) = v;
        }
        __syncthreads();
        const ushort* wcb = wconv + cv * 102400 + ci0 + quad * 8;
#pragma unroll
        for (int dy = 0; dy < 5; ++dy)
#pragma unroll
            for (int dx = 0; dx < 5; ++dx) {
                const int tap = dy * 5 + dx;
                s16x8 a[4];
#pragma unroll
                for (int mt = 0; mt < 4; ++mt)
                    a[mt] = *(const s16x8*)(sm + (dy * 132 + pmc + mt * 16 + n16 + dx) * 32 + quad * 8);
#pragma unroll
                for (int ct = 0; ct < 4; ++ct) {
                    s16x8 bb = *(const s16x8*)(wcb + tap * 4096 + (ct * 16 + n16) * 64);
#pragma unroll
                    for (int mt = 0; mt < 4; ++mt)
                        accC[mt][ct] = MFMA(a[mt], bb, accC[mt][ct]);
                }
            }
    }

    // ---- exchange conv results + gates through LDS (re-divide pixels) ----
    __syncthreads();
#pragma unroll
    for (int mt = 0; mt < 4; ++mt)
#pragma unroll
        for (int ct = 0; ct < 4; ++ct) {
            int co = ct * 16 + n16;
            float bias = cv ? b_inh[co] : b_exc[co];
#pragma unroll
            for (int r = 0; r < 4; ++r) {
                int p = pmc + mt * 16 + quad * 4 + r;
                sm[cv * 8192 + p * 64 + co] = f2bf(accC[mt][ct][r] + bias);
            }
        }
    {
        unsigned* gm = (unsigned*)(sm + 16384);
#pragma unroll
        for (int mt = 0; mt < 2; ++mt)
#pragma unroll
            for (int ct = 0; ct < 4; ++ct)
#pragma unroll
                for (int r = 0; r < 4; ++r) {
                    int p = pm0 + mt * 16 + quad * 4 + r;
                    gm[p * 64 + ct * 16 + n16] = packIF[mt][ct][r];
                }
    }
    __syncthreads();

    // ---- epilogue: hor, c_next, stores, LN partial sums ----
    float lsum = 0.f, lsq = 0.f;
    {
        const unsigned* gm = (const unsigned*)(sm + 16384);
        const int co0 = (lane & 7) * 8;
        const int pr = lane >> 3;
        const float* cb = c + (size_t)b * CHW + y * IW;
        float* ob = out + HALF + (size_t)b * CHW + y * IW;
#pragma unroll
        for (int it = 0; it < 4; ++it) {
            int p = pm0 + it * 8 + pr;
            s16x8 ev8 = *(const s16x8*)(sm + p * 64 + co0);
            s16x8 iv8 = *(const s16x8*)(sm + 8192 + p * 64 + co0);
            s16x8 hc8 = *(const s16x8*)(hrow + p * 64 + co0);
#pragma unroll
            for (int j = 0; j < 8; ++j) {
                int co = co0 + j;
                unsigned pk = gm[p * 64 + co];
                float ig = bf2f((ushort)(pk & 0xffffu));
                float fg = bf2f((ushort)(pk >> 16));
                float ev = bf2f((ushort)ev8[j]);
                float iv = bf2f((ushort)iv8[j]);
                float hc = bf2f((ushort)hc8[j]);
                float hor = sigf(-iv) * (hc + ev);
                float cold = cb[(size_t)co * PLANE + p];
                float cn = fg * cold + ig * hor;
                ob[(size_t)co * PLANE + p] = cn;
                lsum += cn; lsq += cn * cn;
            }
        }
    }
#pragma unroll
    for (int off = 32; off > 0; off >>= 1) {
        lsum += __shfl_down(lsum, off, 64);
        lsq  += __shfl_down(lsq, off, 64);
    }
    if (lane == 0) { reds[w] = lsum; redq[w] = lsq; }
    __syncthreads();
    if (tid == 0) {
        atomicAdd(&red[2 * b], reds[0] + reds[1] + reds[2] + reds[3]);
        atomicAdd(&red[2 * b + 1], redq[0] + redq[1] + redq[2] + redq[3]);
    }
}

// ---- LayerNorm + tanh + o-gate multiply ----
__global__ __launch_bounds__(256) void k_norm(float* __restrict__ out, const float* __restrict__ red)
{
    const float invN = 1.0f / (float)CHW;
    size_t idx = ((size_t)blockIdx.x * 256 + threadIdx.x) * 4;
    int b = (int)(idx >> 20);
    float s = red[2 * b], q = red[2 * b + 1];
    float mean = s * invN;
    float var = q * invN - mean * mean;
    float r = rsqrtf(var + EPS);
    float4 o = *(const float4*)(out + idx);
    float4 cn = *(const float4*)(out + HALF + idx);
    float4 hnv;
    hnv.x = o.x * tanhfast((cn.x - mean) * r);
    hnv.y = o.y * tanhfast((cn.y - mean) * r);
    hnv.z = o.z * tanhfast((cn.z - mean) * r);
    hnv.w = o.w * tanhfast((cn.w - mean) * r);
    *(float4*)(out + idx) = hnv;
}

extern "C" void kernel_launch(void* const* d_in, const int* in_sizes, int n_in,
                              void* d_out, int out_size, void* d_ws, size_t ws_size,
                              hipStream_t stream) {
    const float* x     = (const float*)d_in[0];
    const float* h     = (const float*)d_in[1];
    const float* c     = (const float*)d_in[2];
    const float* w_xg  = (const float*)d_in[3];
    const float* b_xg  = (const float*)d_in[4];
    const float* w_hg  = (const float*)d_in[5];
    const float* b_hg  = (const float*)d_in[6];
    const float* w_exc = (const float*)d_in[7];
    const float* b_exc = (const float*)d_in[8];
    const float* w_inh = (const float*)d_in[9];
    const float* b_inh = (const float*)d_in[10];
    float* out = (float*)d_out;
    char* wsb = (char*)d_ws;
    float* red = (float*)wsb;
    ushort* wconv = (ushort*)(wsb + WS_WCONV);
    ushort* wgate = (ushort*)(wsb + WS_WGATE);
    ushort* xnh = (ushort*)(wsb + WS_XN);
    ushort* hnh = (ushort*)(wsb + WS_HN);

    hipMemsetAsync(red, 0, 256, stream);
    k_prep_w<<<896, 256, 0, stream>>>(w_xg, w_hg, w_exc, w_inh, wconv, wgate);
    k_nhwc<<<8192, 256, 0, stream>>>(x, h, xnh, hnh);
    k_cell<<<4096, 256, 0, stream>>>(xnh, hnh, c, wconv, wgate,
                                     b_xg, b_hg, b_exc, b_inh, out, red);
    k_norm<<<32768, 256, 0, stream>>>(out, red);
}